// Round 9
// baseline (199.709 us; speedup 1.0000x reference)
//
#include <hip/hip_runtime.h>

// VQ-VAE vector quantization forward — MFMA fast-path + exact np recheck.
// x: [32,64,64,64] f32 -> flat [N=131072, D=64]; embeddings: [D=64, K=512].
//
// Exactness contract (validated rounds 2-8 at absmax 0.0): chosen index per
// row == np argmin over dist_k = fl(fl(A+B_k) - fl(2*sim_k)), first-min tie;
// A = np pairwise 8-acc sum(f*f); B_k = sequential sum(e*e); sim = sequential
// FMA chain over d. out = fl(x + fl(q-x)); loss = 1.25*mean((q-x)^2).
//
// Round 9 — kill the epilogue kernel (r8: ~75us of aux kernels, epi's emb
// gather touched 16 cache lines/thread via 2KB-stride reads):
//  - embT[512][64] transposed codebook in ws (prep): row gather = contiguous
//    float4/thread.
//  - Epilogue FUSED into vq_main (round-6-validated code + embT + LDS bx).
//    Flagged rows written with fast index; vq_fix rewrites those ~100 rows
//    np-exactly and atomically adjusts loss by (new_sum - old_sum); delta
//    rounding ~1e-5 on an 8.4e6 accumulator, 6 orders under threshold.
//  - slow list packs (row<<9)|fast_idx; global bx array dropped.
// MFMA core byte-identical to r8 (58us, VGPR 32, MfmaUtil 23%, validated).

constexpr int D = 64;
constexpr int K = 512;
constexpr int NROWS = 131072;
constexpr long long NELEM = 8388608LL;
constexpr int RPB = 64;
constexpr float THRESH = 1e-3f;
constexpr int SLOWCAP = 16384;

typedef __attribute__((ext_vector_type(8))) short bf16x8;
typedef __attribute__((ext_vector_type(4))) float f32x4;

__device__ __forceinline__ unsigned short bf16_rne(float f) {
    unsigned int u = __float_as_uint(f);
    unsigned int r = u + 0x7fffu + ((u >> 16) & 1u);
    return (unsigned short)(r >> 16);
}
__device__ __forceinline__ float bf16_f(unsigned short h) {
    return __uint_as_float(((unsigned int)h) << 16);
}

// ws map (float offsets): 0 loss | 1 cnt | 64 e2[512] | 1024 ebf (128KB)
// | 33792 embT[512*64] | 66560 slow[16384] ints. Total ~332 KB.

// Prep (8x64): e2 np-exact, fragment-ordered bf16 split table, embT.
__global__ __launch_bounds__(64) void vq_prep(const float* __restrict__ emb,
                                              float* __restrict__ e2,
                                              unsigned short* __restrict__ ebf,
                                              float* __restrict__ embT,
                                              float* __restrict__ loss_acc,
                                              int* __restrict__ cnt) {
    const int c = blockIdx.x * 64 + threadIdx.x;
    const int t = c >> 4, m = c & 15;
    float b = 0.f;
#pragma unroll
    for (int d = 0; d < D; ++d) {
        float e = emb[d * K + c];  // coalesced across 64 threads
        embT[c * D + d] = e;
        float sq = __fmul_rn(e, e);
        b = (d == 0) ? sq : __fadd_rn(b, sq);  // np axis-0 sequential order
        unsigned short h1 = bf16_rne(e);
        unsigned short h2 = bf16_rne(e - bf16_f(h1));
        const int q = (d >> 3) & 3, j = d & 7, half = d >> 5;
        const int base = t * 2048 + (q * 16 + m) * 8 + j;
        ebf[base + half * 512] = h1;
        ebf[base + 1024 + half * 512] = h2;
    }
    e2[c] = b;
    if (c == 0) { loss_acc[0] = 0.f; cnt[0] = 0; }
}

// Main: MFMA argmin (r8-validated) + fused epilogue (r6-validated) + loss.
__global__ __launch_bounds__(256, 4) void vq_main(
    const float* __restrict__ x, const float* __restrict__ e2g,
    const unsigned short* __restrict__ ebf, const float* __restrict__ embT,
    float* __restrict__ out, float* __restrict__ loss_acc,
    int* __restrict__ slow, int* __restrict__ cnt) {
    const int tid = threadIdx.x;
    const int l = tid & 63;
    const int wv = tid >> 6;
    const int m = l & 15, q = l >> 4;

    __shared__ int bxl[RPB];
    __shared__ float wsum[4];

    // A-fragments straight from global (16 rows/wave, each lane 2x32B).
    bf16x8 a10, a11, a20, a21;
    {
        const float* xr =
            x + ((size_t)blockIdx.x * RPB + wv * 16 + m) * D + q * 8;
        float4 v0 = *reinterpret_cast<const float4*>(xr);
        float4 v1 = *reinterpret_cast<const float4*>(xr + 4);
        float4 v2 = *reinterpret_cast<const float4*>(xr + 32);
        float4 v3 = *reinterpret_cast<const float4*>(xr + 36);
        float h0[8] = {v0.x, v0.y, v0.z, v0.w, v1.x, v1.y, v1.z, v1.w};
        float h1f[8] = {v2.x, v2.y, v2.z, v2.w, v3.x, v3.y, v3.z, v3.w};
        union { bf16x8 v; unsigned short u[8]; } u10, u11, u20, u21;
#pragma unroll
        for (int j = 0; j < 8; ++j) {
            unsigned short p = bf16_rne(h0[j]), r = bf16_rne(h1f[j]);
            u10.u[j] = p; u11.u[j] = r;
            u20.u[j] = bf16_rne(h0[j] - bf16_f(p));
            u21.u[j] = bf16_rne(h1f[j] - bf16_f(r));
        }
        a10 = u10.v; a11 = u11.v; a20 = u20.v; a21 = u21.v;
    }

    float m1[4], m2[4];
    int i1[4];
#pragma unroll
    for (int g = 0; g < 4; ++g) { m1[g] = 3.0e38f; m2[g] = 3.0e38f; i1[g] = 0; }

#pragma unroll 2
    for (int t = 0; t < 32; ++t) {
        const unsigned short* tb = ebf + t * 2048 + l * 8;
        bf16x8 b10 = *reinterpret_cast<const bf16x8*>(tb);         // coalesced
        bf16x8 b11 = *reinterpret_cast<const bf16x8*>(tb + 512);   // 1KB/load
        bf16x8 b20 = *reinterpret_cast<const bf16x8*>(tb + 1024);
        bf16x8 b21 = *reinterpret_cast<const bf16x8*>(tb + 1536);
        const float Bn = e2g[t * 16 + m];
        f32x4 cp = {0.f, 0.f, 0.f, 0.f}, cq = {0.f, 0.f, 0.f, 0.f};
        // two independent 4-chains (full split product incl. x2*e2)
        cp = __builtin_amdgcn_mfma_f32_16x16x32_bf16(a10, b10, cp, 0, 0, 0);
        cq = __builtin_amdgcn_mfma_f32_16x16x32_bf16(a20, b10, cq, 0, 0, 0);
        cp = __builtin_amdgcn_mfma_f32_16x16x32_bf16(a11, b11, cp, 0, 0, 0);
        cq = __builtin_amdgcn_mfma_f32_16x16x32_bf16(a21, b11, cq, 0, 0, 0);
        cp = __builtin_amdgcn_mfma_f32_16x16x32_bf16(a20, b20, cp, 0, 0, 0);
        cq = __builtin_amdgcn_mfma_f32_16x16x32_bf16(a10, b20, cq, 0, 0, 0);
        cp = __builtin_amdgcn_mfma_f32_16x16x32_bf16(a21, b21, cp, 0, 0, 0);
        cq = __builtin_amdgcn_mfma_f32_16x16x32_bf16(a11, b21, cq, 0, 0, 0);
        const int col = t * 16 + m;
#pragma unroll
        for (int g = 0; g < 4; ++g) {
            float s = fmaf(-2.f, cp[g] + cq[g], Bn);
            bool lt1 = s < m1[g];
            m2[g] = lt1 ? m1[g] : (s < m2[g] ? s : m2[g]);
            if (lt1) { m1[g] = s; i1[g] = col; }
        }
    }

    // Combine across the 16 lanes of each quad (validated rounds 7-8).
#pragma unroll
    for (int g = 0; g < 4; ++g) {
#pragma unroll
        for (int off = 1; off < 16; off <<= 1) {
            float o1 = __shfl_xor(m1[g], off, 64);
            int oi = __shfl_xor(i1[g], off, 64);
            float o2 = __shfl_xor(m2[g], off, 64);
            float nm2 = fminf(fmaxf(m1[g], o1), fminf(m2[g], o2));
            bool take = (o1 < m1[g]) || (o1 == m1[g] && oi < i1[g]);
            if (take) { m1[g] = o1; i1[g] = oi; }
            m2[g] = nm2;  // equal mins, diff idx -> gap 0 -> slow path
        }
        if (m == 0) {
            const int rl = wv * 16 + q * 4 + g;  // row in block
            bxl[rl] = i1[g];
            if (!((m2[g] - m1[g]) > THRESH)) {
                int p = atomicAdd(cnt, 1);
                if (p < SLOWCAP)
                    slow[p] = ((blockIdx.x * RPB + rl) << 9) | i1[g];
            }
        }
    }
    __syncthreads();

    // Fused epilogue (round-6 code + embT contiguous gather). x re-read is
    // L1-hot (this block just loaded it for the fragments).
    float lsum = 0.f;
#pragma unroll
    for (int j = 0; j < 4; ++j) {
        const int e4 = j * 256 + tid;
        const int rr2 = e4 >> 4;
        const int d0 = (e4 & 15) * 4;
        const size_t gbase = (size_t)(blockIdx.x * RPB + rr2) * D + d0;
        const float4 xv = *reinterpret_cast<const float4*>(x + gbase);
        const float4 qv =
            *reinterpret_cast<const float4*>(embT + bxl[rr2] * D + d0);
        float4 o;
        float t;
        t = __fsub_rn(qv.x, xv.x); lsum = __fmaf_rn(t, t, lsum);
        o.x = __fadd_rn(xv.x, t);
        t = __fsub_rn(qv.y, xv.y); lsum = __fmaf_rn(t, t, lsum);
        o.y = __fadd_rn(xv.y, t);
        t = __fsub_rn(qv.z, xv.z); lsum = __fmaf_rn(t, t, lsum);
        o.z = __fadd_rn(xv.z, t);
        t = __fsub_rn(qv.w, xv.w); lsum = __fmaf_rn(t, t, lsum);
        o.w = __fadd_rn(xv.w, t);
        *reinterpret_cast<float4*>(out + gbase) = o;
    }
#pragma unroll
    for (int off = 32; off > 0; off >>= 1) lsum += __shfl_down(lsum, off, 64);
    if (l == 0) wsum[wv] = lsum;
    __syncthreads();
    if (tid == 0)
        atomicAdd(loss_acc, wsum[0] + wsum[1] + wsum[2] + wsum[3]);
}

// Fix: exact np rescan of flagged rows (wave per row); rewrites the out row
// np-exactly and adjusts loss by (new_sum - old_sum).
__global__ __launch_bounds__(256) void vq_fix(const float* __restrict__ x,
                                              const float* __restrict__ emb,
                                              const float* __restrict__ embT,
                                              const float* __restrict__ e2g,
                                              const int* __restrict__ slow,
                                              const int* __restrict__ cnt,
                                              float* __restrict__ out,
                                              float* __restrict__ loss_acc) {
    int n = cnt[0];
    if (n > SLOWCAP) n = SLOWCAP;
    const int lane = threadIdx.x & 63;
    const int wg = blockIdx.x * 4 + (threadIdx.x >> 6);
#pragma unroll 1
    for (int i = wg; i < n; i += 128 * 4) {
        const int entry = __builtin_amdgcn_readfirstlane(slow[i]);
        const int row = entry >> 9;
        const int fidx = entry & 511;
        const float* fr = x + (size_t)row * D;  // uniform -> scalar loads
        // A: np pairwise 8-accumulator path (round-2 validated)
        float r8[8];
#pragma unroll
        for (int j = 0; j < 8; ++j) r8[j] = __fmul_rn(fr[j], fr[j]);
#pragma unroll
        for (int ii = 8; ii < D; ii += 8)
#pragma unroll
            for (int j = 0; j < 8; ++j)
                r8[j] = __fadd_rn(r8[j], __fmul_rn(fr[ii + j], fr[ii + j]));
        const float A = __fadd_rn(
            __fadd_rn(__fadd_rn(r8[0], r8[1]), __fadd_rn(r8[2], r8[3])),
            __fadd_rn(__fadd_rn(r8[4], r8[5]), __fadd_rn(r8[6], r8[7])));
        // 8 codes/lane (c = lane + 64u), sequential FMA chain over d each.
        float acc[8];
#pragma unroll
        for (int u = 0; u < 8; ++u) acc[u] = 0.f;
#pragma unroll
        for (int d = 0; d < D; ++d) {
            const float fd = fr[d];
#pragma unroll
            for (int u = 0; u < 8; ++u)
                acc[u] = __fmaf_rn(fd, emb[d * K + lane + 64 * u], acc[u]);
        }
        float bv = 3.0e38f;
        int bi = 0;
#pragma unroll
        for (int u = 0; u < 8; ++u) {
            const int c = lane + 64 * u;
            float dv = __fsub_rn(__fadd_rn(A, e2g[c]), __fmul_rn(2.f, acc[u]));
            if (dv < bv) { bv = dv; bi = c; }  // ascending c within lane
        }
#pragma unroll
        for (int off = 1; off < 64; off <<= 1) {
            float ov = __shfl_xor(bv, off, 64);
            int oi = __shfl_xor(bi, off, 64);
            if (ov < bv || (ov == bv && oi < bi)) { bv = ov; bi = oi; }
        }
        // Rewrite the row np-exactly with bi; loss delta vs fast index fidx.
        float part = 0.f;
        if (lane < 16) {
            const int d0 = lane * 4;
            const float4 xv =
                *reinterpret_cast<const float4*>(x + (size_t)row * D + d0);
            const float4 qo =
                *reinterpret_cast<const float4*>(embT + fidx * D + d0);
            const float4 qn =
                *reinterpret_cast<const float4*>(embT + bi * D + d0);
            float so = 0.f, sn = 0.f, t;
            float4 o;
            t = __fsub_rn(qo.x, xv.x); so = __fmaf_rn(t, t, so);
            t = __fsub_rn(qo.y, xv.y); so = __fmaf_rn(t, t, so);
            t = __fsub_rn(qo.z, xv.z); so = __fmaf_rn(t, t, so);
            t = __fsub_rn(qo.w, xv.w); so = __fmaf_rn(t, t, so);
            t = __fsub_rn(qn.x, xv.x); sn = __fmaf_rn(t, t, sn);
            o.x = __fadd_rn(xv.x, t);
            t = __fsub_rn(qn.y, xv.y); sn = __fmaf_rn(t, t, sn);
            o.y = __fadd_rn(xv.y, t);
            t = __fsub_rn(qn.z, xv.z); sn = __fmaf_rn(t, t, sn);
            o.z = __fadd_rn(xv.z, t);
            t = __fsub_rn(qn.w, xv.w); sn = __fmaf_rn(t, t, sn);
            o.w = __fadd_rn(xv.w, t);
            *reinterpret_cast<float4*>(out + (size_t)row * D + d0) = o;
            part = sn - so;  // exactly 0 when bi == fidx
        }
#pragma unroll
        for (int off = 32; off > 0; off >>= 1)
            part += __shfl_down(part, off, 64);
        if (lane == 0 && part != 0.f) atomicAdd(loss_acc, part);
    }
}

__global__ void vq_finalize(const float* __restrict__ loss_acc,
                            float* __restrict__ out_loss) {
    if (threadIdx.x == 0) {
        float mm = loss_acc[0] / (float)NELEM;  // /2^23: exact
        out_loss[0] = 1.25f * mm;               // == fl(0.25m + m)
    }
}

extern "C" void kernel_launch(void* const* d_in, const int* in_sizes, int n_in,
                              void* d_out, int out_size, void* d_ws, size_t ws_size,
                              hipStream_t stream) {
    const float* x = (const float*)d_in[0];
    const float* emb = (const float*)d_in[1];
    float* out = (float*)d_out;

    float* ws = (float*)d_ws;
    float* loss_acc = ws;
    int* cnt = (int*)ws + 1;
    float* e2 = ws + 64;
    unsigned short* ebf = (unsigned short*)(ws + 1024);  // 128 KB
    float* embT = ws + 33792;                            // 128 KB
    int* slow = (int*)(ws + 66560);                      // 64 KB

    vq_prep<<<8, 64, 0, stream>>>(emb, e2, ebf, embT, loss_acc, cnt);
    vq_main<<<NROWS / RPB, 256, 0, stream>>>(x, e2, ebf, embT, out, loss_acc,
                                             slow, cnt);
    vq_fix<<<128, 256, 0, stream>>>(x, emb, embT, e2, slow, cnt, out, loss_acc);
    vq_finalize<<<1, 64, 0, stream>>>(loss_acc, out + NELEM);
}

// Round 10
// 178.142 us; speedup vs baseline: 1.1211x; 1.1211x over previous
//
#include <hip/hip_runtime.h>

// VQ-VAE vector quantization forward — MFMA fast-path + exact np recheck.
// x: [32,64,64,64] f32 -> flat [N=131072, D=64]; embeddings: [D=64, K=512].
//
// Exactness contract (validated rounds 2-9 at absmax 0.0): chosen index per
// row == np argmin over dist_k = fl(fl(A+B_k) - fl(2*sim_k)), first-min tie;
// A = np pairwise 8-acc sum(f*f); B_k = sequential sum(e*e); sim = sequential
// FMA chain over d. out = fl(x + fl(q-x)); loss = 1.25*mean((q-x)^2).
//
// Round 10 — the two items the r9 books exposed:
//  - vq_prep was ~35us (8 blocks x 64 thr; every inst a 64-line scatter).
//    Now 8 x 256 with LDS-staged transpose: coalesced global loads, e2 in
//    np-exact order from LDS, embT via dwordx4, ebf via uint4. Target ~5us.
//  - vq_main streamed the 256KB ebf table per 16 rows (~1GB L2 traffic,
//    ~30us of its 86). Now 32 rows/wave (2 row-tiles sharing B-frags):
//    halves table traffic, 4 independent MFMA chains. Grid 1024.
// vq_fix / finalize / margin logic / layouts: byte-identical to r9.

constexpr int D = 64;
constexpr int K = 512;
constexpr int NROWS = 131072;
constexpr long long NELEM = 8388608LL;
constexpr int RPB = 128;     // rows per block (2 row-tiles per wave)
constexpr float THRESH = 1e-3f;
constexpr int SLOWCAP = 16384;

typedef __attribute__((ext_vector_type(8))) short bf16x8;
typedef __attribute__((ext_vector_type(4))) float f32x4;

__device__ __forceinline__ unsigned short bf16_rne(float f) {
    unsigned int u = __float_as_uint(f);
    unsigned int r = u + 0x7fffu + ((u >> 16) & 1u);
    return (unsigned short)(r >> 16);
}
__device__ __forceinline__ float bf16_f(unsigned short h) {
    return __uint_as_float(((unsigned int)h) << 16);
}

// ws map (float offsets): 0 loss | 1 cnt | 64 e2[512] | 1024 ebf (128KB)
// | 33792 embT[512*64] | 66560 slow[16384] ints.

// Prep: 8 blocks x 256. Block b owns codes [b*64, b*64+64).
__global__ __launch_bounds__(256) void vq_prep(const float* __restrict__ emb,
                                               float* __restrict__ e2,
                                               unsigned short* __restrict__ ebf,
                                               float* __restrict__ embT,
                                               float* __restrict__ loss_acc,
                                               int* __restrict__ cnt) {
    const int tid = threadIdx.x;
    const int b = blockIdx.x;
    const int c0 = b * 64;
    __shared__ float se[64 * 65];  // se[d*65 + c_local]

    // Stage: 64 d x 64 codes, coalesced 256B segments (4 d's per iter).
    {
        const int wv = tid >> 6, cl = tid & 63;
#pragma unroll
        for (int it = 0; it < 16; ++it) {
            const int d = it * 4 + wv;
            se[d * 65 + cl] = emb[d * K + c0 + cl];
        }
    }
    __syncthreads();

    // e2: np axis-0 sequential order (identical rounding chain to r9).
    if (tid < 64) {
        const int cl = tid;
        float bacc = __fmul_rn(se[cl], se[cl]);
#pragma unroll
        for (int d = 1; d < 64; ++d) {
            float e = se[d * 65 + cl];
            bacc = __fadd_rn(bacc, __fmul_rn(e, e));
        }
        e2[c0 + cl] = bacc;
    }

    // embT[c][d]: dwordx4 coalesced writes (1024 float4 / 256 thr = 4 iters).
#pragma unroll
    for (int it = 0; it < 4; ++it) {
        const int idx = it * 256 + tid;     // float4 index in 64x64 tile
        const int cl = idx >> 4;
        const int d0 = (idx & 15) * 4;
        float4 v;
        v.x = se[(d0 + 0) * 65 + cl];
        v.y = se[(d0 + 1) * 65 + cl];
        v.z = se[(d0 + 2) * 65 + cl];
        v.w = se[(d0 + 3) * 65 + cl];
        *reinterpret_cast<float4*>(embT + (size_t)(c0 + cl) * D + d0) = v;
    }

    // ebf: block owns tiles t = b*4 .. b*4+3 (8192 shorts = 1024 uint4).
    // layout (r9-identical): tile*2048 + table*1024 + half*512 + lane*8 + j,
    // value = split_table( e[d = q*8+j+32*half][c = tile*16 + (lane&15)] ).
#pragma unroll
    for (int it = 0; it < 4; ++it) {
        const int w = it * 256 + tid;       // uint4 index within block's span
        const int tl = w >> 8;              // local tile 0..3
        const int rem = w & 255;
        const int table = rem >> 7;
        const int half = (rem >> 6) & 1;
        const int lane = rem & 63;
        const int q = lane >> 4, mm = lane & 15;
        const int cl = tl * 16 + mm;
        unsigned short v[8];
#pragma unroll
        for (int j = 0; j < 8; ++j) {
            const float e = se[(q * 8 + j + 32 * half) * 65 + cl];
            unsigned short h1 = bf16_rne(e);
            v[j] = table ? bf16_rne(e - bf16_f(h1)) : h1;
        }
        *reinterpret_cast<uint4*>(ebf + (size_t)(b * 4 + tl) * 2048 +
                                  table * 1024 + half * 512 + lane * 8) =
            *reinterpret_cast<const uint4*>(&v[0]);
    }

    if (b == 0 && tid == 0) { loss_acc[0] = 0.f; cnt[0] = 0; }
}

// Main: MFMA argmin, 2 row-tiles/wave + fused epilogue + loss.
__global__ __launch_bounds__(256, 4) void vq_main(
    const float* __restrict__ x, const float* __restrict__ e2g,
    const unsigned short* __restrict__ ebf, const float* __restrict__ embT,
    float* __restrict__ out, float* __restrict__ loss_acc,
    int* __restrict__ slow, int* __restrict__ cnt) {
    const int tid = threadIdx.x;
    const int l = tid & 63;
    const int wv = tid >> 6;
    const int m = l & 15, q = l >> 4;

    __shared__ int bxl[RPB];
    __shared__ float wsum[4];

    // A-fragments for 2 row-tiles (rows wv*32 + rt*16 + m).
    bf16x8 a10[2], a11[2], a20[2], a21[2];
#pragma unroll
    for (int rt = 0; rt < 2; ++rt) {
        const float* xr =
            x + ((size_t)blockIdx.x * RPB + wv * 32 + rt * 16 + m) * D + q * 8;
        float4 v0 = *reinterpret_cast<const float4*>(xr);
        float4 v1 = *reinterpret_cast<const float4*>(xr + 4);
        float4 v2 = *reinterpret_cast<const float4*>(xr + 32);
        float4 v3 = *reinterpret_cast<const float4*>(xr + 36);
        float h0[8] = {v0.x, v0.y, v0.z, v0.w, v1.x, v1.y, v1.z, v1.w};
        float h1f[8] = {v2.x, v2.y, v2.z, v2.w, v3.x, v3.y, v3.z, v3.w};
        union { bf16x8 v; unsigned short u[8]; } u10, u11, u20, u21;
#pragma unroll
        for (int j = 0; j < 8; ++j) {
            unsigned short p = bf16_rne(h0[j]), r = bf16_rne(h1f[j]);
            u10.u[j] = p; u11.u[j] = r;
            u20.u[j] = bf16_rne(h0[j] - bf16_f(p));
            u21.u[j] = bf16_rne(h1f[j] - bf16_f(r));
        }
        a10[rt] = u10.v; a11[rt] = u11.v; a20[rt] = u20.v; a21[rt] = u21.v;
    }

    float m1[2][4], m2[2][4];
    int i1[2][4];
#pragma unroll
    for (int rt = 0; rt < 2; ++rt)
#pragma unroll
        for (int g = 0; g < 4; ++g) {
            m1[rt][g] = 3.0e38f; m2[rt][g] = 3.0e38f; i1[rt][g] = 0;
        }

#pragma unroll 2
    for (int t = 0; t < 32; ++t) {
        const unsigned short* tb = ebf + t * 2048 + l * 8;
        bf16x8 b10 = *reinterpret_cast<const bf16x8*>(tb);       // coalesced
        bf16x8 b11 = *reinterpret_cast<const bf16x8*>(tb + 512); // 1KB/load
        bf16x8 b20 = *reinterpret_cast<const bf16x8*>(tb + 1024);
        bf16x8 b21 = *reinterpret_cast<const bf16x8*>(tb + 1536);
        const float Bn = e2g[t * 16 + m];
        const int col = t * 16 + m;
        f32x4 cp[2], cq[2];
#pragma unroll
        for (int rt = 0; rt < 2; ++rt) {
            cp[rt] = f32x4{0.f, 0.f, 0.f, 0.f};
            cq[rt] = f32x4{0.f, 0.f, 0.f, 0.f};
        }
        // 16 MFMAs as 4 independent 4-chains (full split product).
#pragma unroll
        for (int rt = 0; rt < 2; ++rt) {
            cp[rt] = __builtin_amdgcn_mfma_f32_16x16x32_bf16(a10[rt], b10, cp[rt], 0, 0, 0);
            cq[rt] = __builtin_amdgcn_mfma_f32_16x16x32_bf16(a20[rt], b10, cq[rt], 0, 0, 0);
            cp[rt] = __builtin_amdgcn_mfma_f32_16x16x32_bf16(a11[rt], b11, cp[rt], 0, 0, 0);
            cq[rt] = __builtin_amdgcn_mfma_f32_16x16x32_bf16(a21[rt], b11, cq[rt], 0, 0, 0);
            cp[rt] = __builtin_amdgcn_mfma_f32_16x16x32_bf16(a20[rt], b20, cp[rt], 0, 0, 0);
            cq[rt] = __builtin_amdgcn_mfma_f32_16x16x32_bf16(a10[rt], b20, cq[rt], 0, 0, 0);
            cp[rt] = __builtin_amdgcn_mfma_f32_16x16x32_bf16(a21[rt], b21, cp[rt], 0, 0, 0);
            cq[rt] = __builtin_amdgcn_mfma_f32_16x16x32_bf16(a11[rt], b21, cq[rt], 0, 0, 0);
        }
#pragma unroll
        for (int rt = 0; rt < 2; ++rt)
#pragma unroll
            for (int g = 0; g < 4; ++g) {
                float s = fmaf(-2.f, cp[rt][g] + cq[rt][g], Bn);
                bool lt1 = s < m1[rt][g];
                m2[rt][g] = lt1 ? m1[rt][g] : (s < m2[rt][g] ? s : m2[rt][g]);
                if (lt1) { m1[rt][g] = s; i1[rt][g] = col; }
            }
    }

    // Combine across the 16 lanes of each quad (validated rounds 7-9).
#pragma unroll
    for (int rt = 0; rt < 2; ++rt)
#pragma unroll
        for (int g = 0; g < 4; ++g) {
#pragma unroll
            for (int off = 1; off < 16; off <<= 1) {
                float o1 = __shfl_xor(m1[rt][g], off, 64);
                int oi = __shfl_xor(i1[rt][g], off, 64);
                float o2 = __shfl_xor(m2[rt][g], off, 64);
                float nm2 =
                    fminf(fmaxf(m1[rt][g], o1), fminf(m2[rt][g], o2));
                bool take = (o1 < m1[rt][g]) ||
                            (o1 == m1[rt][g] && oi < i1[rt][g]);
                if (take) { m1[rt][g] = o1; i1[rt][g] = oi; }
                m2[rt][g] = nm2;  // equal mins, diff idx -> gap 0 -> slow
            }
            if (m == 0) {
                const int rl = wv * 32 + rt * 16 + q * 4 + g;  // row in block
                bxl[rl] = i1[rt][g];
                if (!((m2[rt][g] - m1[rt][g]) > THRESH)) {
                    int p = atomicAdd(cnt, 1);
                    if (p < SLOWCAP)
                        slow[p] = ((blockIdx.x * RPB + rl) << 9) | i1[rt][g];
                }
            }
        }
    __syncthreads();

    // Fused epilogue (r6-validated numerics, embT contiguous gather).
    float lsum = 0.f;
#pragma unroll
    for (int j = 0; j < 8; ++j) {
        const int e4 = j * 256 + tid;
        const int rr2 = e4 >> 4;
        const int d0 = (e4 & 15) * 4;
        const size_t gbase = (size_t)(blockIdx.x * RPB + rr2) * D + d0;
        const float4 xv = *reinterpret_cast<const float4*>(x + gbase);
        const float4 qv =
            *reinterpret_cast<const float4*>(embT + bxl[rr2] * D + d0);
        float4 o;
        float t;
        t = __fsub_rn(qv.x, xv.x); lsum = __fmaf_rn(t, t, lsum);
        o.x = __fadd_rn(xv.x, t);
        t = __fsub_rn(qv.y, xv.y); lsum = __fmaf_rn(t, t, lsum);
        o.y = __fadd_rn(xv.y, t);
        t = __fsub_rn(qv.z, xv.z); lsum = __fmaf_rn(t, t, lsum);
        o.z = __fadd_rn(xv.z, t);
        t = __fsub_rn(qv.w, xv.w); lsum = __fmaf_rn(t, t, lsum);
        o.w = __fadd_rn(xv.w, t);
        *reinterpret_cast<float4*>(out + gbase) = o;
    }
#pragma unroll
    for (int off = 32; off > 0; off >>= 1) lsum += __shfl_down(lsum, off, 64);
    if (l == 0) wsum[wv] = lsum;
    __syncthreads();
    if (tid == 0)
        atomicAdd(loss_acc, wsum[0] + wsum[1] + wsum[2] + wsum[3]);
}

// Fix: exact np rescan of flagged rows (wave per row); rewrites the out row
// np-exactly and adjusts loss by (new_sum - old_sum). r9-validated.
__global__ __launch_bounds__(256) void vq_fix(const float* __restrict__ x,
                                              const float* __restrict__ emb,
                                              const float* __restrict__ embT,
                                              const float* __restrict__ e2g,
                                              const int* __restrict__ slow,
                                              const int* __restrict__ cnt,
                                              float* __restrict__ out,
                                              float* __restrict__ loss_acc) {
    int n = cnt[0];
    if (n > SLOWCAP) n = SLOWCAP;
    const int lane = threadIdx.x & 63;
    const int wg = blockIdx.x * 4 + (threadIdx.x >> 6);
#pragma unroll 1
    for (int i = wg; i < n; i += 128 * 4) {
        const int entry = __builtin_amdgcn_readfirstlane(slow[i]);
        const int row = entry >> 9;
        const int fidx = entry & 511;
        const float* fr = x + (size_t)row * D;  // uniform -> scalar loads
        float r8[8];
#pragma unroll
        for (int j = 0; j < 8; ++j) r8[j] = __fmul_rn(fr[j], fr[j]);
#pragma unroll
        for (int ii = 8; ii < D; ii += 8)
#pragma unroll
            for (int j = 0; j < 8; ++j)
                r8[j] = __fadd_rn(r8[j], __fmul_rn(fr[ii + j], fr[ii + j]));
        const float A = __fadd_rn(
            __fadd_rn(__fadd_rn(r8[0], r8[1]), __fadd_rn(r8[2], r8[3])),
            __fadd_rn(__fadd_rn(r8[4], r8[5]), __fadd_rn(r8[6], r8[7])));
        float acc[8];
#pragma unroll
        for (int u = 0; u < 8; ++u) acc[u] = 0.f;
#pragma unroll
        for (int d = 0; d < D; ++d) {
            const float fd = fr[d];
#pragma unroll
            for (int u = 0; u < 8; ++u)
                acc[u] = __fmaf_rn(fd, emb[d * K + lane + 64 * u], acc[u]);
        }
        float bv = 3.0e38f;
        int bi = 0;
#pragma unroll
        for (int u = 0; u < 8; ++u) {
            const int c = lane + 64 * u;
            float dv = __fsub_rn(__fadd_rn(A, e2g[c]), __fmul_rn(2.f, acc[u]));
            if (dv < bv) { bv = dv; bi = c; }  // ascending c within lane
        }
#pragma unroll
        for (int off = 1; off < 64; off <<= 1) {
            float ov = __shfl_xor(bv, off, 64);
            int oi = __shfl_xor(bi, off, 64);
            if (ov < bv || (ov == bv && oi < bi)) { bv = ov; bi = oi; }
        }
        float part = 0.f;
        if (lane < 16) {
            const int d0 = lane * 4;
            const float4 xv =
                *reinterpret_cast<const float4*>(x + (size_t)row * D + d0);
            const float4 qo =
                *reinterpret_cast<const float4*>(embT + fidx * D + d0);
            const float4 qn =
                *reinterpret_cast<const float4*>(embT + bi * D + d0);
            float so = 0.f, sn = 0.f, t;
            float4 o;
            t = __fsub_rn(qo.x, xv.x); so = __fmaf_rn(t, t, so);
            t = __fsub_rn(qo.y, xv.y); so = __fmaf_rn(t, t, so);
            t = __fsub_rn(qo.z, xv.z); so = __fmaf_rn(t, t, so);
            t = __fsub_rn(qo.w, xv.w); so = __fmaf_rn(t, t, so);
            t = __fsub_rn(qn.x, xv.x); sn = __fmaf_rn(t, t, sn);
            o.x = __fadd_rn(xv.x, t);
            t = __fsub_rn(qn.y, xv.y); sn = __fmaf_rn(t, t, sn);
            o.y = __fadd_rn(xv.y, t);
            t = __fsub_rn(qn.z, xv.z); sn = __fmaf_rn(t, t, sn);
            o.z = __fadd_rn(xv.z, t);
            t = __fsub_rn(qn.w, xv.w); sn = __fmaf_rn(t, t, sn);
            o.w = __fadd_rn(xv.w, t);
            *reinterpret_cast<float4*>(out + (size_t)row * D + d0) = o;
            part = sn - so;  // exactly 0 when bi == fidx
        }
#pragma unroll
        for (int off = 32; off > 0; off >>= 1)
            part += __shfl_down(part, off, 64);
        if (lane == 0 && part != 0.f) atomicAdd(loss_acc, part);
    }
}

__global__ void vq_finalize(const float* __restrict__ loss_acc,
                            float* __restrict__ out_loss) {
    if (threadIdx.x == 0) {
        float mm = loss_acc[0] / (float)NELEM;  // /2^23: exact
        out_loss[0] = 1.25f * mm;               // == fl(0.25m + m)
    }
}

extern "C" void kernel_launch(void* const* d_in, const int* in_sizes, int n_in,
                              void* d_out, int out_size, void* d_ws, size_t ws_size,
                              hipStream_t stream) {
    const float* x = (const float*)d_in[0];
    const float* emb = (const float*)d_in[1];
    float* out = (float*)d_out;

    float* ws = (float*)d_ws;
    float* loss_acc = ws;
    int* cnt = (int*)ws + 1;
    float* e2 = ws + 64;
    unsigned short* ebf = (unsigned short*)(ws + 1024);  // 128 KB
    float* embT = ws + 33792;                            // 128 KB
    int* slow = (int*)(ws + 66560);                      // 64 KB

    vq_prep<<<8, 256, 0, stream>>>(emb, e2, ebf, embT, loss_acc, cnt);
    vq_main<<<NROWS / RPB, 256, 0, stream>>>(x, e2, ebf, embT, out, loss_acc,
                                             slow, cnt);
    vq_fix<<<128, 256, 0, stream>>>(x, emb, embT, e2, slow, cnt, out, loss_acc);
    vq_finalize<<<1, 64, 0, stream>>>(loss_acc, out + NELEM);
}